// Round 17
// baseline (456.131 us; speedup 1.0000x reference)
//
#include <hip/hip_runtime.h>
#include <stdint.h>

// Model6Main: graph-attention recommender forward. f32 inputs/outputs.
// Design: 1 wave per row (lane = feature dim, F=64), f32 compute. R14 structure.
//  - R17: fix W2-f32 LDS swizzle. R16's 32B-chunk XOR (^f&15) gave only 4 start-bank
//    spans -> 16 lanes/span -> 2x LDS cycles (SQ_LDS_BANK_CONFLICT 34.6M, ~17% of
//    runtime). New: 16B chunks XOR f&31 -> 8 spans, 8 lanes/span = conflict-free min.
//  - R16: W2 f32 in LDS (32KB, 6/7 matmuls; no bf16 unpack), W1 bf16 (16KB). 473->327us.
//  - R14: 512-thread blocks, launch_bounds(512,4): natural ~52 VGPR, zero spill.
//  - R12: v_pk_fma_f32 matmul + both W LDS-resident, one barrier.
//  - R11: wsum xor1/2/4/8 via DPP + xor16 ds_swizzle + xor32 shfl.
//  - 4 history mean-pools via ballot histograms w/ constexpr-variable masks (R4: 4.7x)
//  - Launch-bounds/spill law (R2-R15): allocator clamps VGPR to ~256/min_waves and
//    pays with scratch; dur tracks spill traffic (WRITE_SIZE >> out size = spills).

#define DEV __device__ __forceinline__
typedef uint16_t u16;
typedef uint32_t u32;
typedef unsigned long long u64;
typedef float f32x2 __attribute__((ext_vector_type(2)));

static constexpr float EPS_F = 1e-6f;
static constexpr int UOFFS[7] = {0, 11577, 11588, 11599, 11610, 11621, 11642};
static constexpr int ROFFS[5] = {0, 4733, 4754, 4761, 4772};

struct M7s { u64 m[7]; };
struct M5s { u64 m[5]; };
static constexpr M7s gen7(int lim) { M7s r{}; for (int l = 0; l < lim; l++) r.m[l % 7] |= 1ull << l; return r; }
static constexpr M5s gen5(int lim) { M5s r{}; for (int l = 0; l < lim; l++) r.m[l % 5] |= 1ull << l; return r; }
static constexpr M7s M7_64 = gen7(64);   // lanes l<64 with l%7==s
static constexpr M7s M7_12 = gen7(12);
static constexpr M5s M5_64 = gen5(64);
static constexpr M5s M5_36 = gen5(36);

DEV u16 f2bf(float v) { u32 x; __builtin_memcpy(&x, &v, 4); u32 r = x + 0x7FFFu + ((x >> 16) & 1u); return (u16)(r >> 16); }
DEV float lo16f(u32 u) { u32 x = u << 16; float f; __builtin_memcpy(&f, &x, 4); return f; }
DEV float hi16f(u32 u) { u32 x = u & 0xFFFF0000u; float f; __builtin_memcpy(&f, &x, 4); return f; }
DEV float rcpf_(float x) { return __builtin_amdgcn_rcpf(x); }

// ---- wave-64 sum: 4 DPP steps (VALU) + xor16 swizzle + xor32 shfl ----
template <int CTRL>
DEV float dppadd(float v) {
  union { float f; int i; } u, r;
  u.f = v;
  r.i = __builtin_amdgcn_update_dpp(0, u.i, CTRL, 0xF, 0xF, true);
  return v + r.f;
}
DEV float wsum(float v) {
  v = dppadd<0xB1>(v);    // quad_perm [1,0,3,2]  : xor 1
  v = dppadd<0x4E>(v);    // quad_perm [2,3,0,1]  : xor 2
  v = dppadd<0x141>(v);   // row_half_mirror      : xor 4
  v = dppadd<0x140>(v);   // row_mirror           : xor 8
  {                       // xor 16 within 32-lane group
    union { float f; int i; } u, r;
    u.f = v;
    r.i = __builtin_amdgcn_ds_swizzle(u.i, 0x401F);
    v += r.f;
  }
  v += __shfl_xor(v, 32); // cross-32
  return v;
}

// ---- embeds: idx values live in lanes of idxreg; lane reads its own feature f ----
DEV float uembed7(const float* __restrict__ tab, int f, int idxreg, int base) {
  float e = 0.f;
#pragma unroll
  for (int t = 0; t < 7; t++) {
    int ix = __builtin_amdgcn_readlane(idxreg, base + t) + UOFFS[t];
    e += tab[ix * 64 + f];
  }
  return e;
}
DEV float rembed5(const float* __restrict__ tab, int f, int idxreg, int base) {
  float e = 0.f;
#pragma unroll
  for (int t = 0; t < 5; t++) {
    int ix = __builtin_amdgcn_readlane(idxreg, base + t) + ROFFS[t];
    e += tab[ix * 64 + f];
  }
  return e;
}

// ---- ballot-histogram mean pools (indices in [0,7) by construction) ----
DEV float hist_user(const float* __restrict__ tab, int f, int r0, int r1, int r2) {
  float acc = 0.f;
#pragma unroll
  for (int v = 0; v < 7; v++) {
    u64 b0 = __ballot(r0 == v), b1 = __ballot(r1 == v), b2 = __ballot(r2 == v);
#pragma unroll
    for (int t = 0; t < 7; t++) {
      // chunk1 starts at pos 64 (64%7==1): l%7 == (t+6)%7 ; chunk2 at 128 (128%7==2), l<12
      int cnt = __popcll(b0 & M7_64.m[t])
              + __popcll(b1 & M7_64.m[(t + 6) % 7])
              + __popcll(b2 & M7_12.m[(t + 5) % 7]);
      acc = fmaf((float)cnt, tab[(UOFFS[t] + v) * 64 + f], acc);
    }
  }
  return acc * 0.05f;
}

DEV float hist_url(const float* __restrict__ tab, int f, int r0, int r1) {
  float acc = 0.f;
#pragma unroll
  for (int v = 0; v < 7; v++) {
    u64 b0 = __ballot(r0 == v), b1 = __ballot(r1 == v);
#pragma unroll
    for (int t = 0; t < 5; t++) {
      // chunk1 starts at pos 64 (64%5==4): l%5 == (t+1)%5, l<36
      int cnt = __popcll(b0 & M5_64.m[t])
              + __popcll(b1 & M5_36.m[(t + 1) % 5]);
      acc = fmaf((float)cnt, tab[(ROFFS[t] + v) * 64 + f], acc);
    }
  }
  return acc * 0.05f;
}

// ---- shared GAT inner: cos_sim vs center, softmax over 3, weighted relu sum ----
DEV float gat2_inner(float c, float nb, float a0, float a1, float a2, const float* __restrict__ wp) {
  float n0 = wsum(a0 * c), q0 = wsum(a0 * a0);
  float n1 = wsum(a1 * c), q1 = wsum(a1 * a1);
  float n2 = wsum(a2 * c), q2 = wsum(a2 * a2);
  float s0 = n0 * rcpf_(fmaxf(sqrtf(q0), EPS_F) * nb);
  float s1 = n1 * rcpf_(fmaxf(sqrtf(q1), EPS_F) * nb);
  float s2 = n2 * rcpf_(fmaxf(sqrtf(q2), EPS_F) * nb);
  float m = fmaxf(s0, fmaxf(s1, s2));
  float e0 = __expf(s0 - m), e1 = __expf(s1 - m), e2 = __expf(s2 - m);
  float r = rcpf_(e0 + e1 + e2);
  float w0 = wp[0], w1 = wp[1], w2 = wp[2];
  return (fmaxf(a0 * w0, 0.f) * e0 + fmaxf(a1 * w1, 0.f) * e1 + fmaxf(a2 * w2, 0.f) * e2) * r;
}

// bf16 LDS u16 position for W element (f=col, i=row): dword-packed, 16B-chunk XOR swizzle.
DEV int pos16(int ff, int ii) {
  int d = ii >> 1;
  int P = (ff << 6) | ((((d >> 2) ^ (ff & 15)) << 2)) | (d & 3);
  return (P << 1) | (ii & 1);
}

// Stage a 128x64 f32 weight matrix into LDS as bf16 in the swizzled layout.
DEV void stageWbf(u16* __restrict__ s, const float* __restrict__ g, int tid, int nthr) {
  for (int j = tid; j < 8192; j += nthr) {
    int i = j >> 6;        // W row (0..127)
    int fA = j & 63;       // W col (0..63)
    s[pos16(fA, i)] = f2bf(g[j]);
  }
}

// Stage a 128x64 f32 weight matrix into LDS as f32, per-f rows of 128, swizzled
// in 16B (4-f32) chunks XOR f&31: element i of row f at
// (f<<7) + (((i>>2)^(f&31))<<2) + (i&3).  (R17: 8 start-bank spans, conflict-free.)
DEV void stageWf32(float* __restrict__ s, const float* __restrict__ g, int tid, int nthr) {
  for (int j = tid; j < 8192; j += nthr) {
    int i = j >> 6;        // W row (0..127)
    int fA = j & 63;       // W col (0..63)
    s[(fA << 7) + (((i >> 2) ^ (fA & 31)) << 2) + (i & 3)] = g[j];
  }
}

// x(128) @ W(128x64), W f32 in swizzled LDS: 2x ds_read_b128 W + 4 pk_fma per cc.
DEV float matmul128f(const float* __restrict__ wt, float* xl, float x0, float x1, float bias, int f) {
  xl[f] = x0;
  xl[64 + f] = x1;
  f32x2 accA = {0.f, 0.f}, accB = {0.f, 0.f};
  const int fs = f & 31;
  const float* wrow = wt + (f << 7);
#pragma unroll
  for (int cc = 0; cc < 16; cc++) {
    float4 wa = *reinterpret_cast<const float4*>(wrow + (((2 * cc) ^ fs) << 2));
    float4 wb = *reinterpret_cast<const float4*>(wrow + (((2 * cc + 1) ^ fs) << 2));
    float4 xa = *reinterpret_cast<const float4*>(xl + (cc << 3));
    float4 xb = *reinterpret_cast<const float4*>(xl + (cc << 3) + 4);
    f32x2 wA0 = {wa.x, wa.y}, wA1 = {wa.z, wa.w};
    f32x2 wB0 = {wb.x, wb.y}, wB1 = {wb.z, wb.w};
    f32x2 pA0 = {xa.x, xa.y}, pA1 = {xa.z, xa.w};
    f32x2 pB0 = {xb.x, xb.y}, pB1 = {xb.z, xb.w};
    asm("v_pk_fma_f32 %0, %2, %3, %0\n\t"
        "v_pk_fma_f32 %1, %4, %5, %1"
        : "+v"(accA), "+v"(accB)
        : "v"(wA0), "v"(pA0), "v"(wA1), "v"(pA1));
    asm("v_pk_fma_f32 %0, %2, %3, %0\n\t"
        "v_pk_fma_f32 %1, %4, %5, %1"
        : "+v"(accA), "+v"(accB)
        : "v"(wB0), "v"(pB0), "v"(wB1), "v"(pB1));
  }
  return accA[0] + accA[1] + accB[0] + accB[1] + bias;
}

// x(128) @ W(128x64), W bf16 in swizzled LDS (used once: W1 / center matmul).
DEV float matmul128(const u32* __restrict__ wt, float* xl, float x0, float x1, float bias, int f) {
  xl[f] = x0;
  xl[64 + f] = x1;
  f32x2 accA = {0.f, 0.f}, accB = {0.f, 0.f};
  const int fs = f & 15;
  const u32* wrow = wt + (f << 6);
#pragma unroll
  for (int cc = 0; cc < 16; cc++) {
    uint4 w4 = *reinterpret_cast<const uint4*>(wrow + ((cc ^ fs) << 2));
    float4 xa = *reinterpret_cast<const float4*>(xl + (cc << 3));
    float4 xb = *reinterpret_cast<const float4*>(xl + (cc << 3) + 4);
    f32x2 w0 = {lo16f(w4.x), hi16f(w4.x)};
    f32x2 w1 = {lo16f(w4.y), hi16f(w4.y)};
    f32x2 w2 = {lo16f(w4.z), hi16f(w4.z)};
    f32x2 w3 = {lo16f(w4.w), hi16f(w4.w)};
    f32x2 p0 = {xa.x, xa.y}, p1 = {xa.z, xa.w};
    f32x2 p2 = {xb.x, xb.y}, p3 = {xb.z, xb.w};
    asm("v_pk_fma_f32 %0, %2, %3, %0\n\t"
        "v_pk_fma_f32 %1, %4, %5, %1"
        : "+v"(accA), "+v"(accB)
        : "v"(w0), "v"(p0), "v"(w1), "v"(p1));
    asm("v_pk_fma_f32 %0, %2, %3, %0\n\t"
        "v_pk_fma_f32 %1, %4, %5, %1"
        : "+v"(accA), "+v"(accB)
        : "v"(w2), "v"(p2), "v"(w3), "v"(p3));
  }
  return accA[0] + accA[1] + accB[0] + accB[1] + bias;
}

#define LDI(p, n) ((p)[lane < (n) ? lane : (n) - 1])

__global__ __launch_bounds__(512, 4)
void model6_kernel(
    const int* __restrict__ user_f, const int* __restrict__ url_f,
    const int* __restrict__ u1u_f, const float* __restrict__ u1u_w,
    const int* __restrict__ u1url_f, const float* __restrict__ u1url_w,
    const int* __restrict__ u2u_f, const float* __restrict__ u2u_w,
    const int* __restrict__ u2url_f, const float* __restrict__ u2url_w,
    const int* __restrict__ url2u_f, const float* __restrict__ url2u_w,
    const int* __restrict__ url2url_f, const float* __restrict__ url2url_w,
    const int* __restrict__ cons_f, const int* __restrict__ nurl_f,
    const int* __restrict__ fru_f, const int* __restrict__ nus_f,
    const float* __restrict__ utab, const float* __restrict__ rtab,
    const float* __restrict__ w2g, const float* __restrict__ b2g,
    const float* __restrict__ w1g, const float* __restrict__ b1g,
    const float* __restrict__ wog, const float* __restrict__ bog,
    float* __restrict__ out, int N) {
  __shared__ float wt2[8192];              // 32 KB W2 f32 (hop2 branches, 6 matmuls)
  __shared__ u32 wt1[4096];                // 16 KB W1 bf16 (center, 1 matmul)
  __shared__ __align__(16) float xbuf[8][128];

  const int tid = threadIdx.x;
  stageWf32(wt2, w2g, tid, 512);
  stageWbf((u16*)wt1, w1g, tid, 512);
  __syncthreads();                         // the ONLY barrier

  const int lane = tid & 63;
  const int wv = tid >> 6;                 // 0..7
  const int row = (int)blockIdx.x * 8 + wv;
  if (row >= N) return;
  const int f = lane;
  float* xl = xbuf[wv];
  const float2* wo2 = (const float2*)wog;  // element i = (c0, c1) of w_out row i

  float p0 = 0.f, p1 = 0.f;                // per-lane head partials
  float n_u1url0, n_u1url1, n_u1url2;
  float n_u1user0, n_u1user1, n_u1user2;
  float2 w;

  // ---- history mean-pools, folded into head immediately ----
  {
    int r0 = LDI(cons_f + (size_t)row * 100, 64);
    int r1 = LDI(cons_f + (size_t)row * 100 + 64, 36);
    float fo = hist_url(rtab, f, r0, r1);
    w = wo2[0 * 64 + f]; p0 = fmaf(fo, w.x, p0); p1 = fmaf(fo, w.y, p1);
    r0 = LDI(nurl_f + (size_t)row * 100, 64);
    r1 = LDI(nurl_f + (size_t)row * 100 + 64, 36);
    fo = hist_url(rtab, f, r0, r1);
    w = wo2[1 * 64 + f]; p0 = fmaf(fo, w.x, p0); p1 = fmaf(fo, w.y, p1);
  }
  {
    int r0 = LDI(fru_f + (size_t)row * 140, 64);
    int r1 = LDI(fru_f + (size_t)row * 140 + 64, 64);
    int r2 = LDI(fru_f + (size_t)row * 140 + 128, 12);
    float fo = hist_user(utab, f, r0, r1, r2);
    w = wo2[2 * 64 + f]; p0 = fmaf(fo, w.x, p0); p1 = fmaf(fo, w.y, p1);
    r0 = LDI(nus_f + (size_t)row * 140, 64);
    r1 = LDI(nus_f + (size_t)row * 140 + 64, 64);
    r2 = LDI(nus_f + (size_t)row * 140 + 128, 12);
    fo = hist_user(utab, f, r0, r1, r2);
    w = wo2[3 * 64 + f]; p0 = fmaf(fo, w.x, p0); p1 = fmaf(fo, w.y, p1);
  }
  // ---- url_embed folded early ----
  {
    const int iurf = LDI(url_f + (size_t)row * 5, 5);
    float url_embed = rembed5(rtab, f, iurf, 0);
    w = wo2[5 * 64 + f]; p0 = fmaf(url_embed, w.x, p0); p1 = fmaf(url_embed, w.y, p1);
  }

  const float b2v = b2g[f];

  // ---- url branch: hop2 -> hop1 (W2, f32) ----
  {
    const int iu1url = LDI(u1url_f + (size_t)row * 15, 15);
    const int iurl2u = LDI(url2u_f + (size_t)row * 63, 63);
    const int iurl2url = LDI(url2url_f + (size_t)row * 45, 45);
#pragma unroll
    for (int k = 0; k < 3; k++) {
      float c = rembed5(rtab, f, iu1url, k * 5);               // ori_u1url[k]
      float nb = fmaxf(sqrtf(wsum(c * c)), EPS_F);
      float a0 = uembed7(utab, f, iurl2u, (k * 3 + 0) * 7);
      float a1 = uembed7(utab, f, iurl2u, (k * 3 + 1) * 7);
      float a2 = uembed7(utab, f, iurl2u, (k * 3 + 2) * 7);
      float g1 = gat2_inner(c, nb, a0, a1, a2, url2u_w + (size_t)row * 9 + k * 3);
      a0 = rembed5(rtab, f, iurl2url, (k * 3 + 0) * 5);
      a1 = rembed5(rtab, f, iurl2url, (k * 3 + 1) * 5);
      a2 = rembed5(rtab, f, iurl2url, (k * 3 + 2) * 5);
      float g2 = gat2_inner(c, nb, a0, a1, a2, url2url_w + (size_t)row * 9 + k * 3);
      float nv = fmaxf(matmul128f(wt2, xl, c, 0.5f * (g1 + g2), b2v, f), 0.f);
      if (k == 0) n_u1url0 = nv; else if (k == 1) n_u1url1 = nv; else n_u1url2 = nv;
    }
  }

  // ---- user branch: hop2 -> hop1 (W2, f32) ----
  {
    const int iu1u = LDI(u1u_f + (size_t)row * 21, 21);
    const int iu2u = LDI(u2u_f + (size_t)row * 63, 63);
    const int iu2url = LDI(u2url_f + (size_t)row * 45, 45);
#pragma unroll
    for (int k = 0; k < 3; k++) {
      float c = uembed7(utab, f, iu1u, k * 7);                 // ori_u1user[k]
      float nb = fmaxf(sqrtf(wsum(c * c)), EPS_F);
      float a0 = uembed7(utab, f, iu2u, (k * 3 + 0) * 7);
      float a1 = uembed7(utab, f, iu2u, (k * 3 + 1) * 7);
      float a2 = uembed7(utab, f, iu2u, (k * 3 + 2) * 7);
      float g1 = gat2_inner(c, nb, a0, a1, a2, u2u_w + (size_t)row * 9 + k * 3);
      a0 = rembed5(rtab, f, iu2url, (k * 3 + 0) * 5);
      a1 = rembed5(rtab, f, iu2url, (k * 3 + 1) * 5);
      a2 = rembed5(rtab, f, iu2url, (k * 3 + 2) * 5);
      float g2 = gat2_inner(c, nb, a0, a1, a2, u2url_w + (size_t)row * 9 + k * 3);
      float nv = fmaxf(matmul128f(wt2, xl, c, 0.5f * (g1 + g2), b2v, f), 0.f);
      if (k == 0) n_u1user0 = nv; else if (k == 1) n_u1user1 = nv; else n_u1user2 = nv;
    }
  }

  // ---- hop1 -> center (W1, bf16) ----
  {
    const int iuf = LDI(user_f + (size_t)row * 7, 7);
    float ori_user = uembed7(utab, f, iuf, 0);
    float nb = fmaxf(sqrtf(wsum(ori_user * ori_user)), EPS_F);
    float new_url = gat2_inner(ori_user, nb, n_u1url0, n_u1url1, n_u1url2, u1url_w + (size_t)row * 3);
    float new_user = gat2_inner(ori_user, nb, n_u1user0, n_u1user1, n_u1user2, u1u_w + (size_t)row * 3);
    const float b1v = b1g[f];
    float user_embed = fmaxf(matmul128(wt1, xl, ori_user, 0.5f * (new_url + new_user), b1v, f), 0.f);
    w = wo2[4 * 64 + f]; p0 = fmaf(user_embed, w.x, p0); p1 = fmaf(user_embed, w.y, p1);
  }

  // ---- final head reduce + softmax ----
  float l0 = wsum(p0) + bog[0];
  float l1 = wsum(p1) + bog[1];
  float mx = fmaxf(l0, l1);
  float e0 = __expf(l0 - mx), e1 = __expf(l1 - mx);
  float rr = rcpf_(e0 + e1);
  if (lane == 0) {
    float2 o; o.x = e0 * rr; o.y = e1 * rr;
    *reinterpret_cast<float2*>(out + (size_t)row * 2) = o;
  }
}

extern "C" void kernel_launch(void* const* d_in, const int* in_sizes, int n_in,
                              void* d_out, int out_size, void* d_ws, size_t ws_size,
                              hipStream_t stream) {
  const int N = in_sizes[1] / 7;  // user_f_list is (N,7)
  const int* user_f      = (const int*)d_in[1];
  const int* url_f       = (const int*)d_in[2];
  const int* u1u_f       = (const int*)d_in[3];
  const float* u1u_w     = (const float*)d_in[4];
  const int* u1url_f     = (const int*)d_in[5];
  const float* u1url_w   = (const float*)d_in[6];
  const int* u2u_f       = (const int*)d_in[7];
  const float* u2u_w     = (const float*)d_in[8];
  const int* u2url_f     = (const int*)d_in[9];
  const float* u2url_w   = (const float*)d_in[10];
  const int* url2u_f     = (const int*)d_in[11];
  const float* url2u_w   = (const float*)d_in[12];
  const int* url2url_f   = (const int*)d_in[13];
  const float* url2url_w = (const float*)d_in[14];
  const int* cons_f      = (const int*)d_in[15];
  const int* nurl_f      = (const int*)d_in[16];
  const int* fru_f       = (const int*)d_in[17];
  const int* nus_f       = (const int*)d_in[18];
  const float* utab      = (const float*)d_in[19];
  const float* rtab      = (const float*)d_in[20];
  const float* w2g       = (const float*)d_in[21];
  const float* b2g       = (const float*)d_in[22];
  const float* w1g       = (const float*)d_in[23];
  const float* b1g       = (const float*)d_in[24];
  const float* wog       = (const float*)d_in[25];
  const float* bog       = (const float*)d_in[26];

  dim3 grid((unsigned)((N + 7) / 8)), block(512);
  model6_kernel<<<grid, block, 0, stream>>>(
      user_f, url_f, u1u_f, u1u_w, u1url_f, u1url_w,
      u2u_f, u2u_w, u2url_f, u2url_w, url2u_f, url2u_w, url2url_f, url2url_w,
      cons_f, nurl_f, fru_f, nus_f, utab, rtab,
      w2g, b2g, w1g, b1g, wog, bog,
      (float*)d_out, N);
}

// Round 18
// 305.234 us; speedup vs baseline: 1.4944x; 1.4944x over previous
//
#include <hip/hip_runtime.h>
#include <stdint.h>

// Model6Main: graph-attention recommender forward. f32 inputs/outputs.
// Design: 1 wave per row (lane = feature dim, F=64), f32 compute. R16 structure.
//  - R18: revert R17 (computed-pair addressing broke the ds_read->pk_fma pipeline:
//    VALUBusy 77->53, dur 327->456 despite conflicts 34.6M->6.3M). Instead fix
//    R16's 4-span bank conflicts by PADDING the W2 row stride 128->132 floats:
//    start bank = (16f + 32*((cc^fs)&3)) mod 128 -> all 8 spans, addressing
//    shape identical to R16 (one base, +16B immediate pair).
//  - R16: W2 f32 in LDS (6/7 matmuls; no bf16 unpack), W1 bf16. 473->327us.
//  - R14: 512-thread blocks, launch_bounds(512,4): natural ~52 VGPR, zero spill.
//  - R12: v_pk_fma_f32 matmul; R11: DPP wsum. R4: constexpr-mask histograms.
//  - Launch-bounds/spill law (R2-R15): allocator clamps VGPR to ~256/min_waves and
//    pays with scratch; dur tracks spill traffic (WRITE_SIZE >> out size = spills).

#define DEV __device__ __forceinline__
typedef uint16_t u16;
typedef uint32_t u32;
typedef unsigned long long u64;
typedef float f32x2 __attribute__((ext_vector_type(2)));

static constexpr float EPS_F = 1e-6f;
static constexpr int UOFFS[7] = {0, 11577, 11588, 11599, 11610, 11621, 11642};
static constexpr int ROFFS[5] = {0, 4733, 4754, 4761, 4772};
static constexpr int WSTRIDE = 132;      // f32 row stride for W2 in LDS (128 + 4 pad)

struct M7s { u64 m[7]; };
struct M5s { u64 m[5]; };
static constexpr M7s gen7(int lim) { M7s r{}; for (int l = 0; l < lim; l++) r.m[l % 7] |= 1ull << l; return r; }
static constexpr M5s gen5(int lim) { M5s r{}; for (int l = 0; l < lim; l++) r.m[l % 5] |= 1ull << l; return r; }
static constexpr M7s M7_64 = gen7(64);   // lanes l<64 with l%7==s
static constexpr M7s M7_12 = gen7(12);
static constexpr M5s M5_64 = gen5(64);
static constexpr M5s M5_36 = gen5(36);

DEV u16 f2bf(float v) { u32 x; __builtin_memcpy(&x, &v, 4); u32 r = x + 0x7FFFu + ((x >> 16) & 1u); return (u16)(r >> 16); }
DEV float lo16f(u32 u) { u32 x = u << 16; float f; __builtin_memcpy(&f, &x, 4); return f; }
DEV float hi16f(u32 u) { u32 x = u & 0xFFFF0000u; float f; __builtin_memcpy(&f, &x, 4); return f; }
DEV float rcpf_(float x) { return __builtin_amdgcn_rcpf(x); }

// ---- wave-64 sum: 4 DPP steps (VALU) + xor16 swizzle + xor32 shfl ----
template <int CTRL>
DEV float dppadd(float v) {
  union { float f; int i; } u, r;
  u.f = v;
  r.i = __builtin_amdgcn_update_dpp(0, u.i, CTRL, 0xF, 0xF, true);
  return v + r.f;
}
DEV float wsum(float v) {
  v = dppadd<0xB1>(v);    // quad_perm [1,0,3,2]  : xor 1
  v = dppadd<0x4E>(v);    // quad_perm [2,3,0,1]  : xor 2
  v = dppadd<0x141>(v);   // row_half_mirror      : xor 4
  v = dppadd<0x140>(v);   // row_mirror           : xor 8
  {                       // xor 16 within 32-lane group
    union { float f; int i; } u, r;
    u.f = v;
    r.i = __builtin_amdgcn_ds_swizzle(u.i, 0x401F);
    v += r.f;
  }
  v += __shfl_xor(v, 32); // cross-32
  return v;
}

// ---- embeds: idx values live in lanes of idxreg; lane reads its own feature f ----
DEV float uembed7(const float* __restrict__ tab, int f, int idxreg, int base) {
  float e = 0.f;
#pragma unroll
  for (int t = 0; t < 7; t++) {
    int ix = __builtin_amdgcn_readlane(idxreg, base + t) + UOFFS[t];
    e += tab[ix * 64 + f];
  }
  return e;
}
DEV float rembed5(const float* __restrict__ tab, int f, int idxreg, int base) {
  float e = 0.f;
#pragma unroll
  for (int t = 0; t < 5; t++) {
    int ix = __builtin_amdgcn_readlane(idxreg, base + t) + ROFFS[t];
    e += tab[ix * 64 + f];
  }
  return e;
}

// ---- ballot-histogram mean pools (indices in [0,7) by construction) ----
DEV float hist_user(const float* __restrict__ tab, int f, int r0, int r1, int r2) {
  float acc = 0.f;
#pragma unroll
  for (int v = 0; v < 7; v++) {
    u64 b0 = __ballot(r0 == v), b1 = __ballot(r1 == v), b2 = __ballot(r2 == v);
#pragma unroll
    for (int t = 0; t < 7; t++) {
      // chunk1 starts at pos 64 (64%7==1): l%7 == (t+6)%7 ; chunk2 at 128 (128%7==2), l<12
      int cnt = __popcll(b0 & M7_64.m[t])
              + __popcll(b1 & M7_64.m[(t + 6) % 7])
              + __popcll(b2 & M7_12.m[(t + 5) % 7]);
      acc = fmaf((float)cnt, tab[(UOFFS[t] + v) * 64 + f], acc);
    }
  }
  return acc * 0.05f;
}

DEV float hist_url(const float* __restrict__ tab, int f, int r0, int r1) {
  float acc = 0.f;
#pragma unroll
  for (int v = 0; v < 7; v++) {
    u64 b0 = __ballot(r0 == v), b1 = __ballot(r1 == v);
#pragma unroll
    for (int t = 0; t < 5; t++) {
      // chunk1 starts at pos 64 (64%5==4): l%5 == (t+1)%5, l<36
      int cnt = __popcll(b0 & M5_64.m[t])
              + __popcll(b1 & M5_36.m[(t + 1) % 5]);
      acc = fmaf((float)cnt, tab[(ROFFS[t] + v) * 64 + f], acc);
    }
  }
  return acc * 0.05f;
}

// ---- shared GAT inner: cos_sim vs center, softmax over 3, weighted relu sum ----
DEV float gat2_inner(float c, float nb, float a0, float a1, float a2, const float* __restrict__ wp) {
  float n0 = wsum(a0 * c), q0 = wsum(a0 * a0);
  float n1 = wsum(a1 * c), q1 = wsum(a1 * a1);
  float n2 = wsum(a2 * c), q2 = wsum(a2 * a2);
  float s0 = n0 * rcpf_(fmaxf(sqrtf(q0), EPS_F) * nb);
  float s1 = n1 * rcpf_(fmaxf(sqrtf(q1), EPS_F) * nb);
  float s2 = n2 * rcpf_(fmaxf(sqrtf(q2), EPS_F) * nb);
  float m = fmaxf(s0, fmaxf(s1, s2));
  float e0 = __expf(s0 - m), e1 = __expf(s1 - m), e2 = __expf(s2 - m);
  float r = rcpf_(e0 + e1 + e2);
  float w0 = wp[0], w1 = wp[1], w2 = wp[2];
  return (fmaxf(a0 * w0, 0.f) * e0 + fmaxf(a1 * w1, 0.f) * e1 + fmaxf(a2 * w2, 0.f) * e2) * r;
}

// bf16 LDS u16 position for W element (f=col, i=row): dword-packed, 16B-chunk XOR swizzle.
DEV int pos16(int ff, int ii) {
  int d = ii >> 1;
  int P = (ff << 6) | ((((d >> 2) ^ (ff & 15)) << 2)) | (d & 3);
  return (P << 1) | (ii & 1);
}

// Stage a 128x64 f32 weight matrix into LDS as bf16 in the swizzled layout.
DEV void stageWbf(u16* __restrict__ s, const float* __restrict__ g, int tid, int nthr) {
  for (int j = tid; j < 8192; j += nthr) {
    int i = j >> 6;        // W row (0..127)
    int fA = j & 63;       // W col (0..63)
    s[pos16(fA, i)] = f2bf(g[j]);
  }
}

// Stage a 128x64 f32 weight matrix into LDS as f32, padded rows of WSTRIDE=132,
// 32B-chunk XOR swizzle (as R16): element i of row f at
// f*132 + (((i>>3)^(f&15))<<3) + (i&7). Pad makes start banks span all 8 16B slots.
DEV void stageWf32(float* __restrict__ s, const float* __restrict__ g, int tid, int nthr) {
  for (int j = tid; j < 8192; j += nthr) {
    int i = j >> 6;        // W row (0..127)
    int fA = j & 63;       // W col (0..63)
    s[fA * WSTRIDE + (((i >> 3) ^ (fA & 15)) << 3) + (i & 7)] = g[j];
  }
}

// x(128) @ W(128x64), W f32 in padded swizzled LDS: 2x ds_read_b128 W + 4 pk_fma per cc.
DEV float matmul128f(const float* __restrict__ wt, float* xl, float x0, float x1, float bias, int f) {
  xl[f] = x0;
  xl[64 + f] = x1;
  f32x2 accA = {0.f, 0.f}, accB = {0.f, 0.f};
  const int fs = f & 15;
  const float* wrow = wt + f * WSTRIDE;
#pragma unroll
  for (int cc = 0; cc < 16; cc++) {
    float4 wa = *reinterpret_cast<const float4*>(wrow + ((cc ^ fs) << 3));
    float4 wb = *reinterpret_cast<const float4*>(wrow + ((cc ^ fs) << 3) + 4);
    float4 xa = *reinterpret_cast<const float4*>(xl + (cc << 3));
    float4 xb = *reinterpret_cast<const float4*>(xl + (cc << 3) + 4);
    f32x2 wA0 = {wa.x, wa.y}, wA1 = {wa.z, wa.w};
    f32x2 wB0 = {wb.x, wb.y}, wB1 = {wb.z, wb.w};
    f32x2 pA0 = {xa.x, xa.y}, pA1 = {xa.z, xa.w};
    f32x2 pB0 = {xb.x, xb.y}, pB1 = {xb.z, xb.w};
    asm("v_pk_fma_f32 %0, %2, %3, %0\n\t"
        "v_pk_fma_f32 %1, %4, %5, %1"
        : "+v"(accA), "+v"(accB)
        : "v"(wA0), "v"(pA0), "v"(wA1), "v"(pA1));
    asm("v_pk_fma_f32 %0, %2, %3, %0\n\t"
        "v_pk_fma_f32 %1, %4, %5, %1"
        : "+v"(accA), "+v"(accB)
        : "v"(wB0), "v"(pB0), "v"(wB1), "v"(pB1));
  }
  return accA[0] + accA[1] + accB[0] + accB[1] + bias;
}

// x(128) @ W(128x64), W bf16 in swizzled LDS (used once: W1 / center matmul).
DEV float matmul128(const u32* __restrict__ wt, float* xl, float x0, float x1, float bias, int f) {
  xl[f] = x0;
  xl[64 + f] = x1;
  f32x2 accA = {0.f, 0.f}, accB = {0.f, 0.f};
  const int fs = f & 15;
  const u32* wrow = wt + (f << 6);
#pragma unroll
  for (int cc = 0; cc < 16; cc++) {
    uint4 w4 = *reinterpret_cast<const uint4*>(wrow + ((cc ^ fs) << 2));
    float4 xa = *reinterpret_cast<const float4*>(xl + (cc << 3));
    float4 xb = *reinterpret_cast<const float4*>(xl + (cc << 3) + 4);
    f32x2 w0 = {lo16f(w4.x), hi16f(w4.x)};
    f32x2 w1 = {lo16f(w4.y), hi16f(w4.y)};
    f32x2 w2 = {lo16f(w4.z), hi16f(w4.z)};
    f32x2 w3 = {lo16f(w4.w), hi16f(w4.w)};
    f32x2 p0 = {xa.x, xa.y}, p1 = {xa.z, xa.w};
    f32x2 p2 = {xb.x, xb.y}, p3 = {xb.z, xb.w};
    asm("v_pk_fma_f32 %0, %2, %3, %0\n\t"
        "v_pk_fma_f32 %1, %4, %5, %1"
        : "+v"(accA), "+v"(accB)
        : "v"(w0), "v"(p0), "v"(w1), "v"(p1));
    asm("v_pk_fma_f32 %0, %2, %3, %0\n\t"
        "v_pk_fma_f32 %1, %4, %5, %1"
        : "+v"(accA), "+v"(accB)
        : "v"(w2), "v"(p2), "v"(w3), "v"(p3));
  }
  return accA[0] + accA[1] + accB[0] + accB[1] + bias;
}

#define LDI(p, n) ((p)[lane < (n) ? lane : (n) - 1])

__global__ __launch_bounds__(512, 4)
void model6_kernel(
    const int* __restrict__ user_f, const int* __restrict__ url_f,
    const int* __restrict__ u1u_f, const float* __restrict__ u1u_w,
    const int* __restrict__ u1url_f, const float* __restrict__ u1url_w,
    const int* __restrict__ u2u_f, const float* __restrict__ u2u_w,
    const int* __restrict__ u2url_f, const float* __restrict__ u2url_w,
    const int* __restrict__ url2u_f, const float* __restrict__ url2u_w,
    const int* __restrict__ url2url_f, const float* __restrict__ url2url_w,
    const int* __restrict__ cons_f, const int* __restrict__ nurl_f,
    const int* __restrict__ fru_f, const int* __restrict__ nus_f,
    const float* __restrict__ utab, const float* __restrict__ rtab,
    const float* __restrict__ w2g, const float* __restrict__ b2g,
    const float* __restrict__ w1g, const float* __restrict__ b1g,
    const float* __restrict__ wog, const float* __restrict__ bog,
    float* __restrict__ out, int N) {
  __shared__ float wt2[64 * WSTRIDE];      // 33 KB W2 f32, padded rows (6 matmuls)
  __shared__ u32 wt1[4096];                // 16 KB W1 bf16 (center, 1 matmul)
  __shared__ __align__(16) float xbuf[8][128];

  const int tid = threadIdx.x;
  stageWf32(wt2, w2g, tid, 512);
  stageWbf((u16*)wt1, w1g, tid, 512);
  __syncthreads();                         // the ONLY barrier

  const int lane = tid & 63;
  const int wv = tid >> 6;                 // 0..7
  const int row = (int)blockIdx.x * 8 + wv;
  if (row >= N) return;
  const int f = lane;
  float* xl = xbuf[wv];
  const float2* wo2 = (const float2*)wog;  // element i = (c0, c1) of w_out row i

  float p0 = 0.f, p1 = 0.f;                // per-lane head partials
  float n_u1url0, n_u1url1, n_u1url2;
  float n_u1user0, n_u1user1, n_u1user2;
  float2 w;

  // ---- history mean-pools, folded into head immediately ----
  {
    int r0 = LDI(cons_f + (size_t)row * 100, 64);
    int r1 = LDI(cons_f + (size_t)row * 100 + 64, 36);
    float fo = hist_url(rtab, f, r0, r1);
    w = wo2[0 * 64 + f]; p0 = fmaf(fo, w.x, p0); p1 = fmaf(fo, w.y, p1);
    r0 = LDI(nurl_f + (size_t)row * 100, 64);
    r1 = LDI(nurl_f + (size_t)row * 100 + 64, 36);
    fo = hist_url(rtab, f, r0, r1);
    w = wo2[1 * 64 + f]; p0 = fmaf(fo, w.x, p0); p1 = fmaf(fo, w.y, p1);
  }
  {
    int r0 = LDI(fru_f + (size_t)row * 140, 64);
    int r1 = LDI(fru_f + (size_t)row * 140 + 64, 64);
    int r2 = LDI(fru_f + (size_t)row * 140 + 128, 12);
    float fo = hist_user(utab, f, r0, r1, r2);
    w = wo2[2 * 64 + f]; p0 = fmaf(fo, w.x, p0); p1 = fmaf(fo, w.y, p1);
    r0 = LDI(nus_f + (size_t)row * 140, 64);
    r1 = LDI(nus_f + (size_t)row * 140 + 64, 64);
    r2 = LDI(nus_f + (size_t)row * 140 + 128, 12);
    fo = hist_user(utab, f, r0, r1, r2);
    w = wo2[3 * 64 + f]; p0 = fmaf(fo, w.x, p0); p1 = fmaf(fo, w.y, p1);
  }
  // ---- url_embed folded early ----
  {
    const int iurf = LDI(url_f + (size_t)row * 5, 5);
    float url_embed = rembed5(rtab, f, iurf, 0);
    w = wo2[5 * 64 + f]; p0 = fmaf(url_embed, w.x, p0); p1 = fmaf(url_embed, w.y, p1);
  }

  const float b2v = b2g[f];

  // ---- url branch: hop2 -> hop1 (W2, f32) ----
  {
    const int iu1url = LDI(u1url_f + (size_t)row * 15, 15);
    const int iurl2u = LDI(url2u_f + (size_t)row * 63, 63);
    const int iurl2url = LDI(url2url_f + (size_t)row * 45, 45);
#pragma unroll
    for (int k = 0; k < 3; k++) {
      float c = rembed5(rtab, f, iu1url, k * 5);               // ori_u1url[k]
      float nb = fmaxf(sqrtf(wsum(c * c)), EPS_F);
      float a0 = uembed7(utab, f, iurl2u, (k * 3 + 0) * 7);
      float a1 = uembed7(utab, f, iurl2u, (k * 3 + 1) * 7);
      float a2 = uembed7(utab, f, iurl2u, (k * 3 + 2) * 7);
      float g1 = gat2_inner(c, nb, a0, a1, a2, url2u_w + (size_t)row * 9 + k * 3);
      a0 = rembed5(rtab, f, iurl2url, (k * 3 + 0) * 5);
      a1 = rembed5(rtab, f, iurl2url, (k * 3 + 1) * 5);
      a2 = rembed5(rtab, f, iurl2url, (k * 3 + 2) * 5);
      float g2 = gat2_inner(c, nb, a0, a1, a2, url2url_w + (size_t)row * 9 + k * 3);
      float nv = fmaxf(matmul128f(wt2, xl, c, 0.5f * (g1 + g2), b2v, f), 0.f);
      if (k == 0) n_u1url0 = nv; else if (k == 1) n_u1url1 = nv; else n_u1url2 = nv;
    }
  }

  // ---- user branch: hop2 -> hop1 (W2, f32) ----
  {
    const int iu1u = LDI(u1u_f + (size_t)row * 21, 21);
    const int iu2u = LDI(u2u_f + (size_t)row * 63, 63);
    const int iu2url = LDI(u2url_f + (size_t)row * 45, 45);
#pragma unroll
    for (int k = 0; k < 3; k++) {
      float c = uembed7(utab, f, iu1u, k * 7);                 // ori_u1user[k]
      float nb = fmaxf(sqrtf(wsum(c * c)), EPS_F);
      float a0 = uembed7(utab, f, iu2u, (k * 3 + 0) * 7);
      float a1 = uembed7(utab, f, iu2u, (k * 3 + 1) * 7);
      float a2 = uembed7(utab, f, iu2u, (k * 3 + 2) * 7);
      float g1 = gat2_inner(c, nb, a0, a1, a2, u2u_w + (size_t)row * 9 + k * 3);
      a0 = rembed5(rtab, f, iu2url, (k * 3 + 0) * 5);
      a1 = rembed5(rtab, f, iu2url, (k * 3 + 1) * 5);
      a2 = rembed5(rtab, f, iu2url, (k * 3 + 2) * 5);
      float g2 = gat2_inner(c, nb, a0, a1, a2, u2url_w + (size_t)row * 9 + k * 3);
      float nv = fmaxf(matmul128f(wt2, xl, c, 0.5f * (g1 + g2), b2v, f), 0.f);
      if (k == 0) n_u1user0 = nv; else if (k == 1) n_u1user1 = nv; else n_u1user2 = nv;
    }
  }

  // ---- hop1 -> center (W1, bf16) ----
  {
    const int iuf = LDI(user_f + (size_t)row * 7, 7);
    float ori_user = uembed7(utab, f, iuf, 0);
    float nb = fmaxf(sqrtf(wsum(ori_user * ori_user)), EPS_F);
    float new_url = gat2_inner(ori_user, nb, n_u1url0, n_u1url1, n_u1url2, u1url_w + (size_t)row * 3);
    float new_user = gat2_inner(ori_user, nb, n_u1user0, n_u1user1, n_u1user2, u1u_w + (size_t)row * 3);
    const float b1v = b1g[f];
    float user_embed = fmaxf(matmul128(wt1, xl, ori_user, 0.5f * (new_url + new_user), b1v, f), 0.f);
    w = wo2[4 * 64 + f]; p0 = fmaf(user_embed, w.x, p0); p1 = fmaf(user_embed, w.y, p1);
  }

  // ---- final head reduce + softmax ----
  float l0 = wsum(p0) + bog[0];
  float l1 = wsum(p1) + bog[1];
  float mx = fmaxf(l0, l1);
  float e0 = __expf(l0 - mx), e1 = __expf(l1 - mx);
  float rr = rcpf_(e0 + e1);
  if (lane == 0) {
    float2 o; o.x = e0 * rr; o.y = e1 * rr;
    *reinterpret_cast<float2*>(out + (size_t)row * 2) = o;
  }
}

extern "C" void kernel_launch(void* const* d_in, const int* in_sizes, int n_in,
                              void* d_out, int out_size, void* d_ws, size_t ws_size,
                              hipStream_t stream) {
  const int N = in_sizes[1] / 7;  // user_f_list is (N,7)
  const int* user_f      = (const int*)d_in[1];
  const int* url_f       = (const int*)d_in[2];
  const int* u1u_f       = (const int*)d_in[3];
  const float* u1u_w     = (const float*)d_in[4];
  const int* u1url_f     = (const int*)d_in[5];
  const float* u1url_w   = (const float*)d_in[6];
  const int* u2u_f       = (const int*)d_in[7];
  const float* u2u_w     = (const float*)d_in[8];
  const int* u2url_f     = (const int*)d_in[9];
  const float* u2url_w   = (const float*)d_in[10];
  const int* url2u_f     = (const int*)d_in[11];
  const float* url2u_w   = (const float*)d_in[12];
  const int* url2url_f   = (const int*)d_in[13];
  const float* url2url_w = (const float*)d_in[14];
  const int* cons_f      = (const int*)d_in[15];
  const int* nurl_f      = (const int*)d_in[16];
  const int* fru_f       = (const int*)d_in[17];
  const int* nus_f       = (const int*)d_in[18];
  const float* utab      = (const float*)d_in[19];
  const float* rtab      = (const float*)d_in[20];
  const float* w2g       = (const float*)d_in[21];
  const float* b2g       = (const float*)d_in[22];
  const float* w1g       = (const float*)d_in[23];
  const float* b1g       = (const float*)d_in[24];
  const float* wog       = (const float*)d_in[25];
  const float* bog       = (const float*)d_in[26];

  dim3 grid((unsigned)((N + 7) / 8)), block(512);
  model6_kernel<<<grid, block, 0, stream>>>(
      user_f, url_f, u1u_f, u1u_w, u1url_f, u1url_w,
      u2u_f, u2u_w, u2url_f, u2url_w, url2u_f, url2u_w, url2url_f, url2url_w,
      cons_f, nurl_f, fru_f, nus_f, utab, rtab,
      w2g, b2g, w1g, b1g, wog, bog,
      (float*)d_out, N);
}